// Round 11
// baseline (173.161 us; speedup 1.0000x reference)
//
#include <hip/hip_runtime.h>
#include <math.h>

// ---------------------------------------------------------------------------
// MultiGCN: 3-layer GCN, N=50000, E=800000, D=H=128, C=40.
// Round 11:
//  - Gather buffers back to bf16 (int8+rowscale removed): agg edge cost drops
//    from 3 random VMEM streams (csr, row, xscale) to 2; uint4/lane = full
//    256B row per wave-instruction. GEMM epilogue loses the 16-lane absmax
//    reduce + quant.
//  - f32 residual chain removed: h1/h2 live ONLY as bf16 (hb1/hb2). agg-1
//    resid = x (f32, unavoidable); agg-2 resid = hb1 (bf16, half traffic).
//  - csr2 entries loaded pairwise (int4) in agg -> half the csr VMEM instrs.
//  - k_init + wprep(W1,W2) + wprep3(W3) fused into one launch (k_prep).
// CSR build (XCD-replicated count, rank-based no-atomic fill) unchanged.
// ---------------------------------------------------------------------------

#define HD 128   // hidden / input feature dim
#define NC 40    // classes

typedef __attribute__((ext_vector_type(8))) short bfrag;   // 8 bf16 = 4 VGPR
typedef __attribute__((ext_vector_type(4))) float facc;    // 4 f32

// f32 -> bf16 round-to-nearest-even (finite values only)
__device__ __forceinline__ unsigned short f2bf(float f) {
  unsigned int u = __float_as_uint(f);
  u += 0x7FFFu + ((u >> 16) & 1u);
  return (unsigned short)(u >> 16);
}
__device__ __forceinline__ unsigned int packbf2(float a, float b) {
  return (unsigned int)f2bf(a) | ((unsigned int)f2bf(b) << 16);
}
__device__ __forceinline__ float2 bf2f2(unsigned int v) {
  float2 r;
  r.x = __uint_as_float(v << 16);
  r.y = __uint_as_float(v & 0xFFFF0000u);
  return r;
}

#define NCOPY 8  // counter replicas (one per XCD)

// ---- fused prep: cnt8/gtotal init + W1,W2 -> bf16 W^T + W3 -> bf16 [48][128]

__global__ __launch_bounds__(256) void k_prep(
    const float* __restrict__ W1, const float* __restrict__ W2,
    const float* __restrict__ W3,
    unsigned short* __restrict__ W1t, unsigned short* __restrict__ W2t,
    unsigned short* __restrict__ W3t,
    int* __restrict__ cnt8, int* __restrict__ gtotal, int n8) {
  __shared__ unsigned short sh[HD * 136];
  if (blockIdx.x < 2) {
    const float* W = blockIdx.x ? W2 : W1;
    unsigned short* Wt = blockIdx.x ? W2t : W1t;
#pragma unroll
    for (int i = 0; i < 16; ++i) {
      int f4 = i * 256 + threadIdx.x;     // float4 id 0..4095
      int r = f4 >> 5;                    // k row
      int c = (f4 & 31) * 4;              // n col
      float4 v = *(const float4*)(W + r * HD + c);
      sh[(c + 0) * 136 + r] = f2bf(v.x);
      sh[(c + 1) * 136 + r] = f2bf(v.y);
      sh[(c + 2) * 136 + r] = f2bf(v.z);
      sh[(c + 3) * 136 + r] = f2bf(v.w);
    }
    __syncthreads();
#pragma unroll
    for (int i = 0; i < 8; ++i) {
      int g = i * 256 + threadIdx.x;      // 16B chunk id 0..2047
      int nrow = g >> 4, k16 = g & 15;
      uint4 v = *(const uint4*)(&sh[nrow * 136 + k16 * 8]);
      *(uint4*)(Wt + (size_t)g * 8) = v;
    }
  } else if (blockIdx.x == 2) {
    for (int i = threadIdx.x; i < 48 * 136; i += 256) sh[i] = 0;
    __syncthreads();
#pragma unroll
    for (int i = 0; i < 5; ++i) {
      int f4 = i * 256 + threadIdx.x;     // float4 id 0..1279
      if (f4 < 1280) {
        int r = f4 / 10;                  // k row 0..127
        int c = (f4 % 10) * 4;            // col 0..36
        float4 v = *(const float4*)(W3 + r * NC + c);
        sh[(c + 0) * 136 + r] = f2bf(v.x);
        sh[(c + 1) * 136 + r] = f2bf(v.y);
        sh[(c + 2) * 136 + r] = f2bf(v.z);
        sh[(c + 3) * 136 + r] = f2bf(v.w);
      }
    }
    __syncthreads();
#pragma unroll
    for (int i = 0; i < 3; ++i) {
      int g = i * 256 + threadIdx.x;      // 16B chunk id 0..767
      int nrow = g >> 4, k16 = g & 15;
      uint4 v = *(const uint4*)(&sh[nrow * 136 + k16 * 8]);
      *(uint4*)(W3t + (size_t)g * 8) = v;
    }
  } else {
    int i = (blockIdx.x - 3) * 256 + threadIdx.x;
    if (i < n8) cnt8[i] = 0;
    if (i == 0) *gtotal = 0;
  }
}

// ---- CSR build ------------------------------------------------------------

// 1 edge/thread; atomics go to the blockIdx&7 replica (XCD-local heuristic)
__global__ __launch_bounds__(256) void k_count_rank(
    const int* __restrict__ dst, int* __restrict__ cnt8,
    int* __restrict__ rank, int E, int n) {
  int e = blockIdx.x * 256 + threadIdx.x;
  if (e < E) {
    int copy = blockIdx.x & (NCOPY - 1);
    rank[e] = atomicAdd(&cnt8[copy * n + dst[e]], 1);
  }
}

// sum 8 replicas, scan totals, emit per-copy bases (cinfo) + dinv
__global__ __launch_bounds__(256) void k_alloc(
    const int* __restrict__ cnt8, int* __restrict__ row_start,
    int* __restrict__ row_end, int2* __restrict__ cinfo,
    float* __restrict__ dinv, int* __restrict__ gtotal, int n) {
  __shared__ int sh[256];
  __shared__ int base_sh;
  const int tid = threadIdx.x;
  int i = blockIdx.x * 256 + tid;
  int c[NCOPY];
  int v = 0;
  if (i < n) {
#pragma unroll
    for (int j = 0; j < NCOPY; ++j) {
      c[j] = cnt8[j * n + i];
      v += c[j];
    }
  }
  sh[tid] = v;
  __syncthreads();
  for (int off = 1; off < 256; off <<= 1) {
    int t = (tid >= off) ? sh[tid - off] : 0;
    __syncthreads();
    sh[tid] += t;
    __syncthreads();
  }
  if (tid == 255) base_sh = atomicAdd(gtotal, sh[255]);
  __syncthreads();
  if (i < n) {
    int start = base_sh + sh[tid] - v;
    float dv = rsqrtf((float)(v + 1));  // +1 self loop
    row_start[i] = start;
    row_end[i] = start + v;
    dinv[i] = dv;
    int base = start;
#pragma unroll
    for (int j = 0; j < NCOPY; ++j) {
      cinfo[(size_t)j * n + i] = make_int2(base, __float_as_int(dv));
      base += c[j];
    }
  }
}

// fill: no atomics; 1 edge/thread; copy = (e>>8)&7 matches count's blockIdx&7
__global__ __launch_bounds__(256) void k_fill(
    const int* __restrict__ src, const int* __restrict__ dst,
    const int* __restrict__ rank, const int2* __restrict__ cinfo,
    const float* __restrict__ dinv, int2* __restrict__ csr2, int E, int n) {
  int e = blockIdx.x * 256 + threadIdx.x;
  if (e < E) {
    int d = dst[e];
    int s = src[e];
    int r = rank[e];
    int copy = (e >> 8) & (NCOPY - 1);
    int2 ni = cinfo[(size_t)copy * n + d];
    float norm = dinv[s] * __int_as_float(ni.y);
    csr2[ni.x + r] = make_int2(s, __float_as_int(norm));
  }
}

// ---- MFMA GEMM (128 cols), bf16 output ------------------------------------

template <bool A_IS_F32>
__global__ __launch_bounds__(256) void gemm_mfma_f128(
    const float* __restrict__ Af, const unsigned short* __restrict__ Ab,
    const unsigned short* __restrict__ Wt,
    unsigned short* __restrict__ out, int n) {
  __shared__ unsigned short shWt[HD * 136];   // [n][k], pad 8 bf16/row
  {
#pragma unroll
    for (int i = 0; i < 8; ++i) {
      int g = i * 256 + threadIdx.x;          // 16B chunk 0..2047
      int nrow = g >> 4, k16 = g & 15;
      uint4 v = *(const uint4*)(Wt + (size_t)g * 8);
      *(uint4*)(&shWt[nrow * 136 + k16 * 8]) = v;
    }
  }

  const int lane = threadIdx.x & 63;
  const int w = threadIdx.x >> 6;             // wave 0..3
  const int m = blockIdx.x * 64 + w * 16 + (lane & 15);
  const int mc = min(m, n - 1);
  const int kbase = (lane >> 4) * 8;          // 0,8,16,24

  bfrag af[4];
  if constexpr (A_IS_F32) {
    const float* ap = Af + (size_t)mc * HD + kbase;
#pragma unroll
    for (int kk = 0; kk < 4; ++kk) {
      float4 lo = *(const float4*)(ap + kk * 32);
      float4 hi = *(const float4*)(ap + kk * 32 + 4);
      bfrag a;
      a[0] = (short)f2bf(lo.x); a[1] = (short)f2bf(lo.y);
      a[2] = (short)f2bf(lo.z); a[3] = (short)f2bf(lo.w);
      a[4] = (short)f2bf(hi.x); a[5] = (short)f2bf(hi.y);
      a[6] = (short)f2bf(hi.z); a[7] = (short)f2bf(hi.w);
      af[kk] = a;
    }
  } else {
    const unsigned short* ap = Ab + (size_t)mc * HD + kbase;
#pragma unroll
    for (int kk = 0; kk < 4; ++kk) af[kk] = *(const bfrag*)(ap + kk * 32);
  }

  __syncthreads();

  facc acc[8];
#pragma unroll
  for (int c = 0; c < 8; ++c) {
    acc[c][0] = 0.f; acc[c][1] = 0.f; acc[c][2] = 0.f; acc[c][3] = 0.f;
  }

#pragma unroll
  for (int kk = 0; kk < 4; ++kk) {
#pragma unroll
    for (int c = 0; c < 8; ++c) {
      bfrag bf = *(const bfrag*)(&shWt[(c * 16 + (lane & 15)) * 136 + kk * 32 + kbase]);
      acc[c] = __builtin_amdgcn_mfma_f32_16x16x32_bf16(af[kk], bf, acc[c], 0, 0, 0);
    }
  }

  // C layout: col = lane&15, row = (lane>>4)*4 + q (within each 16-row tile).
  const int rbase = blockIdx.x * 64 + w * 16 + (lane >> 4) * 4;
  const int col = lane & 15;
#pragma unroll
  for (int q = 0; q < 4; ++q) {
    int r = rbase + q;
    if (r < n) {
#pragma unroll
      for (int c = 0; c < 8; ++c)
        out[(size_t)r * HD + c * 16 + col] = f2bf(acc[c][q]);
    }
  }
}

// ---- MFMA GEMM (40 cols, padded 48): xw40(bf16) = hb @ W3t^T ---------------

__global__ __launch_bounds__(256) void gemm_mfma_f40(
    const unsigned short* __restrict__ Ab,   // bf16 h2 [n][128]
    const unsigned short* __restrict__ Wt,   // bf16 [48][128]
    unsigned short* __restrict__ out, int n) {
  __shared__ unsigned short shWt[48 * 136];
  {
#pragma unroll
    for (int i = 0; i < 3; ++i) {
      int g = i * 256 + threadIdx.x;          // 16B chunk 0..767
      int nrow = g >> 4, k16 = g & 15;
      uint4 v = *(const uint4*)(Wt + (size_t)g * 8);
      *(uint4*)(&shWt[nrow * 136 + k16 * 8]) = v;
    }
  }

  const int lane = threadIdx.x & 63;
  const int w = threadIdx.x >> 6;
  const int m = blockIdx.x * 64 + w * 16 + (lane & 15);
  const int mc = min(m, n - 1);
  const int kbase = (lane >> 4) * 8;

  bfrag af[4];
  const unsigned short* ap = Ab + (size_t)mc * HD + kbase;
#pragma unroll
  for (int kk = 0; kk < 4; ++kk) af[kk] = *(const bfrag*)(ap + kk * 32);

  __syncthreads();

  facc acc[3];
#pragma unroll
  for (int c = 0; c < 3; ++c) {
    acc[c][0] = 0.f; acc[c][1] = 0.f; acc[c][2] = 0.f; acc[c][3] = 0.f;
  }
#pragma unroll
  for (int kk = 0; kk < 4; ++kk) {
#pragma unroll
    for (int c = 0; c < 3; ++c) {
      bfrag bf = *(const bfrag*)(&shWt[(c * 16 + (lane & 15)) * 136 + kk * 32 + kbase]);
      acc[c] = __builtin_amdgcn_mfma_f32_16x16x32_bf16(af[kk], bf, acc[c], 0, 0, 0);
    }
  }

  const int rbase = blockIdx.x * 64 + w * 16 + (lane >> 4) * 4;
  const int col = lane & 15;
#pragma unroll
  for (int c = 0; c < 3; ++c) {
    int j = c * 16 + col;
    if (j < NC) {
#pragma unroll
      for (int q = 0; q < 4; ++q) {
        int r = rbase + q;
        if (r < n) out[(size_t)r * NC + j] = f2bf(acc[c][q]);
      }
    }
  }
}

// ---- aggregation, F=128 (bf16): 4 nodes/wave, 16 lanes/node, uint4/lane ----
// RESID_F32: layer 1 (resid = x, f32). else resid = bf16 hb row.

template <bool RESID_F32>
__global__ __launch_bounds__(256) void agg_f128(
    const unsigned short* __restrict__ xw,
    const float* __restrict__ residf, const unsigned short* __restrict__ residb,
    const float* __restrict__ bias, const float* __restrict__ dinv,
    const int* __restrict__ row_start, const int* __restrict__ row_end,
    const int2* __restrict__ csr2, unsigned short* __restrict__ hbO, int n) {
  const int node = (blockIdx.x * 256 + threadIdx.x) >> 4;  // 16 threads/node
  if (node >= n) return;
  const int li = threadIdx.x & 15;
  const int f0 = li * 8;

  float di = dinv[node];
  float4 b01 = *(const float4*)(bias + f0);
  float4 b23 = *(const float4*)(bias + f0 + 4);
  // self term
  uint4 su = *(const uint4*)(xw + (size_t)node * HD + f0);
  float ssc = di * di;
  float2 s0 = bf2f2(su.x), s1 = bf2f2(su.y), s2 = bf2f2(su.z), s3 = bf2f2(su.w);
  float a0 = fmaf(s0.x, ssc, b01.x);
  float a1 = fmaf(s0.y, ssc, b01.y);
  float a2 = fmaf(s1.x, ssc, b01.z);
  float a3 = fmaf(s1.y, ssc, b01.w);
  float a4 = fmaf(s2.x, ssc, b23.x);
  float a5 = fmaf(s2.y, ssc, b23.y);
  float a6 = fmaf(s3.x, ssc, b23.z);
  float a7 = fmaf(s3.y, ssc, b23.w);

  int k = row_start[node];
  const int end = row_end[node];
  for (; k + 4 <= end; k += 4) {
    int4 p01 = *(const int4*)(csr2 + k);       // entries k, k+1
    int4 p23 = *(const int4*)(csr2 + k + 2);   // entries k+2, k+3
    uint4 u0 = *(const uint4*)(xw + (size_t)p01.x * HD + f0);
    uint4 u1 = *(const uint4*)(xw + (size_t)p01.z * HD + f0);
    uint4 u2 = *(const uint4*)(xw + (size_t)p23.x * HD + f0);
    uint4 u3 = *(const uint4*)(xw + (size_t)p23.z * HD + f0);
    float w0 = __int_as_float(p01.y), w1 = __int_as_float(p01.w);
    float w2 = __int_as_float(p23.y), w3 = __int_as_float(p23.w);
    float2 v0, v1, v2, v3;
    v0 = bf2f2(u0.x); v1 = bf2f2(u0.y); v2 = bf2f2(u0.z); v3 = bf2f2(u0.w);
    a0 = fmaf(v0.x, w0, a0); a1 = fmaf(v0.y, w0, a1);
    a2 = fmaf(v1.x, w0, a2); a3 = fmaf(v1.y, w0, a3);
    a4 = fmaf(v2.x, w0, a4); a5 = fmaf(v2.y, w0, a5);
    a6 = fmaf(v3.x, w0, a6); a7 = fmaf(v3.y, w0, a7);
    v0 = bf2f2(u1.x); v1 = bf2f2(u1.y); v2 = bf2f2(u1.z); v3 = bf2f2(u1.w);
    a0 = fmaf(v0.x, w1, a0); a1 = fmaf(v0.y, w1, a1);
    a2 = fmaf(v1.x, w1, a2); a3 = fmaf(v1.y, w1, a3);
    a4 = fmaf(v2.x, w1, a4); a5 = fmaf(v2.y, w1, a5);
    a6 = fmaf(v3.x, w1, a6); a7 = fmaf(v3.y, w1, a7);
    v0 = bf2f2(u2.x); v1 = bf2f2(u2.y); v2 = bf2f2(u2.z); v3 = bf2f2(u2.w);
    a0 = fmaf(v0.x, w2, a0); a1 = fmaf(v0.y, w2, a1);
    a2 = fmaf(v1.x, w2, a2); a3 = fmaf(v1.y, w2, a3);
    a4 = fmaf(v2.x, w2, a4); a5 = fmaf(v2.y, w2, a5);
    a6 = fmaf(v3.x, w2, a6); a7 = fmaf(v3.y, w2, a7);
    v0 = bf2f2(u3.x); v1 = bf2f2(u3.y); v2 = bf2f2(u3.z); v3 = bf2f2(u3.w);
    a0 = fmaf(v0.x, w3, a0); a1 = fmaf(v0.y, w3, a1);
    a2 = fmaf(v1.x, w3, a2); a3 = fmaf(v1.y, w3, a3);
    a4 = fmaf(v2.x, w3, a4); a5 = fmaf(v2.y, w3, a5);
    a6 = fmaf(v3.x, w3, a6); a7 = fmaf(v3.y, w3, a7);
  }
  for (; k < end; ++k) {
    int2 c = csr2[k];
    uint4 u = *(const uint4*)(xw + (size_t)c.x * HD + f0);
    float wv = __int_as_float(c.y);
    float2 v0 = bf2f2(u.x), v1 = bf2f2(u.y), v2 = bf2f2(u.z), v3 = bf2f2(u.w);
    a0 = fmaf(v0.x, wv, a0); a1 = fmaf(v0.y, wv, a1);
    a2 = fmaf(v1.x, wv, a2); a3 = fmaf(v1.y, wv, a3);
    a4 = fmaf(v2.x, wv, a4); a5 = fmaf(v2.y, wv, a5);
    a6 = fmaf(v3.x, wv, a6); a7 = fmaf(v3.y, wv, a7);
  }

  float r0, r1, r2, r3, r4, r5, r6, r7;
  if constexpr (RESID_F32) {
    float4 q0 = *(const float4*)(residf + (size_t)node * HD + f0);
    float4 q1 = *(const float4*)(residf + (size_t)node * HD + f0 + 4);
    r0 = q0.x; r1 = q0.y; r2 = q0.z; r3 = q0.w;
    r4 = q1.x; r5 = q1.y; r6 = q1.z; r7 = q1.w;
  } else {
    uint4 q = *(const uint4*)(residb + (size_t)node * HD + f0);
    float2 p0 = bf2f2(q.x), p1 = bf2f2(q.y), p2 = bf2f2(q.z), p3 = bf2f2(q.w);
    r0 = p0.x; r1 = p0.y; r2 = p1.x; r3 = p1.y;
    r4 = p2.x; r5 = p2.y; r6 = p3.x; r7 = p3.y;
  }
  uint4 hv;
  hv.x = packbf2(fmaxf(a0, 0.f) + r0, fmaxf(a1, 0.f) + r1);
  hv.y = packbf2(fmaxf(a2, 0.f) + r2, fmaxf(a3, 0.f) + r3);
  hv.z = packbf2(fmaxf(a4, 0.f) + r4, fmaxf(a5, 0.f) + r5);
  hv.w = packbf2(fmaxf(a6, 0.f) + r6, fmaxf(a7, 0.f) + r7);
  *(uint4*)(hbO + (size_t)node * HD + f0) = hv;
}

// ---- aggregation, F=40 + log_softmax: 4 nodes/wave, 16 lanes/node ---------

__global__ __launch_bounds__(256) void agg_f40_lsm(
    const unsigned short* __restrict__ xw, const float* __restrict__ dinv,
    const int* __restrict__ row_start, const int* __restrict__ row_end,
    const int2* __restrict__ csr2, const float* __restrict__ bias,
    float* __restrict__ out, int n) {
  const int node = (blockIdx.x * 256 + threadIdx.x) >> 4;
  if (node >= n) return;
  const int li = threadIdx.x & 15;
  const bool act = li < 10;
  const int f0 = li * 4;                 // 0..36 for active lanes

  float a0 = 0.f, a1 = 0.f, a2 = 0.f, a3 = 0.f;
  float di = dinv[node];
  if (act) {
    float4 bv = *(const float4*)(bias + f0);
    uint2 su = *(const uint2*)(xw + (size_t)node * NC + f0);
    float2 s0 = bf2f2(su.x), s1 = bf2f2(su.y);
    float ssc = di * di;
    a0 = fmaf(s0.x, ssc, bv.x);
    a1 = fmaf(s0.y, ssc, bv.y);
    a2 = fmaf(s1.x, ssc, bv.z);
    a3 = fmaf(s1.y, ssc, bv.w);
  }

  int k = row_start[node];
  const int end = row_end[node];
  for (; k + 4 <= end; k += 4) {
    int4 p01 = *(const int4*)(csr2 + k);
    int4 p23 = *(const int4*)(csr2 + k + 2);
    if (act) {
      uint2 u0 = *(const uint2*)(xw + (size_t)p01.x * NC + f0);
      uint2 u1 = *(const uint2*)(xw + (size_t)p01.z * NC + f0);
      uint2 u2 = *(const uint2*)(xw + (size_t)p23.x * NC + f0);
      uint2 u3 = *(const uint2*)(xw + (size_t)p23.z * NC + f0);
      float w0 = __int_as_float(p01.y), w1 = __int_as_float(p01.w);
      float w2 = __int_as_float(p23.y), w3 = __int_as_float(p23.w);
      float2 p, q;
      p = bf2f2(u0.x); q = bf2f2(u0.y);
      a0 = fmaf(p.x, w0, a0); a1 = fmaf(p.y, w0, a1);
      a2 = fmaf(q.x, w0, a2); a3 = fmaf(q.y, w0, a3);
      p = bf2f2(u1.x); q = bf2f2(u1.y);
      a0 = fmaf(p.x, w1, a0); a1 = fmaf(p.y, w1, a1);
      a2 = fmaf(q.x, w1, a2); a3 = fmaf(q.y, w1, a3);
      p = bf2f2(u2.x); q = bf2f2(u2.y);
      a0 = fmaf(p.x, w2, a0); a1 = fmaf(p.y, w2, a1);
      a2 = fmaf(q.x, w2, a2); a3 = fmaf(q.y, w2, a3);
      p = bf2f2(u3.x); q = bf2f2(u3.y);
      a0 = fmaf(p.x, w3, a0); a1 = fmaf(p.y, w3, a1);
      a2 = fmaf(q.x, w3, a2); a3 = fmaf(q.y, w3, a3);
    }
  }
  for (; k < end; ++k) {
    int2 c = csr2[k];
    if (act) {
      uint2 u = *(const uint2*)(xw + (size_t)c.x * NC + f0);
      float w = __int_as_float(c.y);
      float2 p = bf2f2(u.x), q = bf2f2(u.y);
      a0 = fmaf(p.x, w, a0); a1 = fmaf(p.y, w, a1);
      a2 = fmaf(q.x, w, a2); a3 = fmaf(q.y, w, a3);
    }
  }

  // log_softmax over the node's 40 values (10 lanes x 4), 16-lane xor reduce
  float m = act ? fmaxf(fmaxf(a0, a1), fmaxf(a2, a3)) : -3.0e38f;
  m = fmaxf(m, __shfl_xor(m, 1, 64));
  m = fmaxf(m, __shfl_xor(m, 2, 64));
  m = fmaxf(m, __shfl_xor(m, 4, 64));
  m = fmaxf(m, __shfl_xor(m, 8, 64));
  float s = act ? (expf(a0 - m) + expf(a1 - m) + expf(a2 - m) + expf(a3 - m)) : 0.f;
  s += __shfl_xor(s, 1, 64);
  s += __shfl_xor(s, 2, 64);
  s += __shfl_xor(s, 4, 64);
  s += __shfl_xor(s, 8, 64);
  if (act) {
    float lse = m + logf(s);
    float4 o;
    o.x = a0 - lse; o.y = a1 - lse; o.z = a2 - lse; o.w = a3 - lse;
    *(float4*)(out + (size_t)node * NC + f0) = o;
  }
}

// ---------------------------------------------------------------------------

extern "C" void kernel_launch(void* const* d_in, const int* in_sizes, int n_in,
                              void* d_out, int out_size, void* d_ws, size_t ws_size,
                              hipStream_t stream) {
  const float* x  = (const float*)d_in[0];
  const int*   ei = (const int*)d_in[1];
  const float* W1 = (const float*)d_in[2];
  const float* b1 = (const float*)d_in[3];
  const float* W2 = (const float*)d_in[4];
  const float* b2 = (const float*)d_in[5];
  const float* W3 = (const float*)d_in[6];
  const float* b3 = (const float*)d_in[7];
  float* out = (float*)d_out;

  const int n = in_sizes[0] / HD;  // 50000
  const int E = in_sizes[1] / 2;   // 800000
  const int* src = ei;
  const int* dst = ei + E;

  // workspace carve (all 256B-aligned)
  char* ws = (char*)d_ws;
  size_t off = 0;
  auto carve = [&](size_t bytes) -> void* {
    void* p = ws + off;
    off += (bytes + 255) & ~(size_t)255;
    return p;
  };
  int*   cnt8      = (int*)carve((size_t)n * NCOPY * 4);
  int*   row_start = (int*)carve((size_t)n * 4);
  int*   row_end   = (int*)carve((size_t)n * 4);
  float* dinv      = (float*)carve((size_t)n * 4);
  int2*  cinfo     = (int2*)carve((size_t)n * NCOPY * 8);
  int*   gtotal    = (int*)carve(256);
  unsigned short* w1t = (unsigned short*)carve((size_t)HD * HD * 2);
  unsigned short* w2t = (unsigned short*)carve((size_t)HD * HD * 2);
  unsigned short* w3t = (unsigned short*)carve((size_t)48 * HD * 2);
  int2*  csr2      = (int2*)carve((size_t)E * 8);
  unsigned short* xwb  = (unsigned short*)carve((size_t)n * HD * 2);  // bf16 xw
  unsigned short* hb1  = (unsigned short*)carve((size_t)n * HD * 2);  // bf16 h1
  unsigned short* hb2  = (unsigned short*)carve((size_t)n * HD * 2);  // bf16 h2
  unsigned short* xw40 = (unsigned short*)carve((size_t)n * NC * 2);  // bf16 xw3
  // rank[] is only live before gemm1 writes xwb -> alias it.
  int*   rank      = (int*)xwb;

  const int gn8  = (n * NCOPY + 255) / 256;
  const int gE1  = (E + 255) / 256;       // 1 edge per thread
  const int gA   = (n + 15) / 16;         // 16 nodes per agg block
  const int gM   = (n + 63) / 64;         // 64 rows per mfma gemm block

  // fused prep (W preps + counter init), then CSR build
  k_prep<<<gn8 + 3, 256, 0, stream>>>(W1, W2, W3, w1t, w2t, w3t, cnt8, gtotal,
                                      n * NCOPY);
  k_count_rank<<<gE1, 256, 0, stream>>>(dst, cnt8, rank, E, n);
  k_alloc<<<(n + 255) / 256, 256, 0, stream>>>(cnt8, row_start, row_end, cinfo, dinv, gtotal, n);
  k_fill<<<gE1, 256, 0, stream>>>(src, dst, rank, cinfo, dinv, csr2, E, n);

  // layer 1: xw = x@W1 -> xwb(bf16) ; h1 = relu(agg)+x -> hb1 (bf16)
  gemm_mfma_f128<true><<<gM, 256, 0, stream>>>(x, (const unsigned short*)nullptr, w1t, xwb, n);
  agg_f128<true><<<gA, 256, 0, stream>>>(xwb, x, (const unsigned short*)nullptr,
                                         b1, dinv, row_start, row_end, csr2, hb1, n);

  // layer 2: xw = h1@W2 -> xwb ; h2 = relu(agg)+h1 -> hb2 (bf16)
  gemm_mfma_f128<false><<<gM, 256, 0, stream>>>((const float*)nullptr, hb1, w2t, xwb, n);
  agg_f128<false><<<gA, 256, 0, stream>>>(xwb, (const float*)nullptr, hb1,
                                          b2, dinv, row_start, row_end, csr2, hb2, n);

  // layer 3: xw = h2@W3 -> xw40(bf16, MFMA) ; out = log_softmax(agg + b3)
  gemm_mfma_f40<<<gM, 256, 0, stream>>>(hb2, w3t, xw40, n);
  agg_f40_lsm<<<gA, 256, 0, stream>>>(xw40, dinv, row_start, row_end, csr2, b3, out, n);
}

// Round 12
// 156.580 us; speedup vs baseline: 1.1059x; 1.1059x over previous
//
#include <hip/hip_runtime.h>
#include <math.h>

// ---------------------------------------------------------------------------
// MultiGCN: 3-layer GCN, N=50000, E=800000, D=H=128, C=40.
// Round 12: recombination of round-10 (int8 gathers -- L2-sector-bound, 2
// sectors/edge beats bf16's 4) with round-11's orthogonal wins:
//  - h1/h2 bf16-only (hb1/hb2): agg-1 drops the 25MB f32 write, agg-2 resid
//    read halves. (absmax unchanged at 0.03125 in both parents.)
//  - csr2 pair-loaded as int4 in agg kernels (half the csr VMEM instrs).
//  - fused k_prep (counter init + W1/W2/W3 bf16 transpose preps).
// CSR build (XCD-replicated count, rank-based no-atomic fill, 1 edge/thread)
// and MFMA GEMMs unchanged. rank aliases xw8 (disjoint live ranges).
// ---------------------------------------------------------------------------

#define HD 128   // hidden / input feature dim
#define NC 40    // classes

typedef __attribute__((ext_vector_type(8))) short bfrag;   // 8 bf16 = 4 VGPR
typedef __attribute__((ext_vector_type(4))) float facc;    // 4 f32

// f32 -> bf16 round-to-nearest-even (finite values only)
__device__ __forceinline__ unsigned short f2bf(float f) {
  unsigned int u = __float_as_uint(f);
  u += 0x7FFFu + ((u >> 16) & 1u);
  return (unsigned short)(u >> 16);
}
__device__ __forceinline__ unsigned int packbf2(float a, float b) {
  return (unsigned int)f2bf(a) | ((unsigned int)f2bf(b) << 16);
}
__device__ __forceinline__ float2 bf2f2(unsigned int v) {
  float2 r;
  r.x = __uint_as_float(v << 16);
  r.y = __uint_as_float(v & 0xFFFF0000u);
  return r;
}
// signed byte i (0..3) of u, as float
__device__ __forceinline__ float db(unsigned int u, int i) {
  return (float)(signed char)((u >> (8 * i)) & 0xFFu);
}

#define NCOPY 8  // counter replicas (one per XCD)

// ---- fused prep: cnt8/gtotal init + W1,W2 -> bf16 W^T + W3 -> bf16 [48][128]

__global__ __launch_bounds__(256) void k_prep(
    const float* __restrict__ W1, const float* __restrict__ W2,
    const float* __restrict__ W3,
    unsigned short* __restrict__ W1t, unsigned short* __restrict__ W2t,
    unsigned short* __restrict__ W3t,
    int* __restrict__ cnt8, int* __restrict__ gtotal, int n8) {
  __shared__ unsigned short sh[HD * 136];
  if (blockIdx.x < 2) {
    const float* W = blockIdx.x ? W2 : W1;
    unsigned short* Wt = blockIdx.x ? W2t : W1t;
#pragma unroll
    for (int i = 0; i < 16; ++i) {
      int f4 = i * 256 + threadIdx.x;     // float4 id 0..4095
      int r = f4 >> 5;                    // k row
      int c = (f4 & 31) * 4;              // n col
      float4 v = *(const float4*)(W + r * HD + c);
      sh[(c + 0) * 136 + r] = f2bf(v.x);
      sh[(c + 1) * 136 + r] = f2bf(v.y);
      sh[(c + 2) * 136 + r] = f2bf(v.z);
      sh[(c + 3) * 136 + r] = f2bf(v.w);
    }
    __syncthreads();
#pragma unroll
    for (int i = 0; i < 8; ++i) {
      int g = i * 256 + threadIdx.x;      // 16B chunk id 0..2047
      int nrow = g >> 4, k16 = g & 15;
      uint4 v = *(const uint4*)(&sh[nrow * 136 + k16 * 8]);
      *(uint4*)(Wt + (size_t)g * 8) = v;
    }
  } else if (blockIdx.x == 2) {
    for (int i = threadIdx.x; i < 48 * 136; i += 256) sh[i] = 0;
    __syncthreads();
#pragma unroll
    for (int i = 0; i < 5; ++i) {
      int f4 = i * 256 + threadIdx.x;     // float4 id 0..1279
      if (f4 < 1280) {
        int r = f4 / 10;                  // k row 0..127
        int c = (f4 % 10) * 4;            // col 0..36
        float4 v = *(const float4*)(W3 + r * NC + c);
        sh[(c + 0) * 136 + r] = f2bf(v.x);
        sh[(c + 1) * 136 + r] = f2bf(v.y);
        sh[(c + 2) * 136 + r] = f2bf(v.z);
        sh[(c + 3) * 136 + r] = f2bf(v.w);
      }
    }
    __syncthreads();
#pragma unroll
    for (int i = 0; i < 3; ++i) {
      int g = i * 256 + threadIdx.x;      // 16B chunk id 0..767
      int nrow = g >> 4, k16 = g & 15;
      uint4 v = *(const uint4*)(&sh[nrow * 136 + k16 * 8]);
      *(uint4*)(W3t + (size_t)g * 8) = v;
    }
  } else {
    int i = (blockIdx.x - 3) * 256 + threadIdx.x;
    if (i < n8) cnt8[i] = 0;
    if (i == 0) *gtotal = 0;
  }
}

// ---- CSR build ------------------------------------------------------------

// 1 edge/thread; atomics go to the blockIdx&7 replica (XCD-local heuristic)
__global__ __launch_bounds__(256) void k_count_rank(
    const int* __restrict__ dst, int* __restrict__ cnt8,
    int* __restrict__ rank, int E, int n) {
  int e = blockIdx.x * 256 + threadIdx.x;
  if (e < E) {
    int copy = blockIdx.x & (NCOPY - 1);
    rank[e] = atomicAdd(&cnt8[copy * n + dst[e]], 1);
  }
}

// sum 8 replicas, scan totals, emit per-copy bases (cinfo) + dinv
__global__ __launch_bounds__(256) void k_alloc(
    const int* __restrict__ cnt8, int* __restrict__ row_start,
    int* __restrict__ row_end, int2* __restrict__ cinfo,
    float* __restrict__ dinv, int* __restrict__ gtotal, int n) {
  __shared__ int sh[256];
  __shared__ int base_sh;
  const int tid = threadIdx.x;
  int i = blockIdx.x * 256 + tid;
  int c[NCOPY];
  int v = 0;
  if (i < n) {
#pragma unroll
    for (int j = 0; j < NCOPY; ++j) {
      c[j] = cnt8[j * n + i];
      v += c[j];
    }
  }
  sh[tid] = v;
  __syncthreads();
  for (int off = 1; off < 256; off <<= 1) {
    int t = (tid >= off) ? sh[tid - off] : 0;
    __syncthreads();
    sh[tid] += t;
    __syncthreads();
  }
  if (tid == 255) base_sh = atomicAdd(gtotal, sh[255]);
  __syncthreads();
  if (i < n) {
    int start = base_sh + sh[tid] - v;
    float dv = rsqrtf((float)(v + 1));  // +1 self loop
    row_start[i] = start;
    row_end[i] = start + v;
    dinv[i] = dv;
    int base = start;
#pragma unroll
    for (int j = 0; j < NCOPY; ++j) {
      cinfo[(size_t)j * n + i] = make_int2(base, __float_as_int(dv));
      base += c[j];
    }
  }
}

// fill: no atomics; 1 edge/thread; copy = (e>>8)&7 matches count's blockIdx&7
__global__ __launch_bounds__(256) void k_fill(
    const int* __restrict__ src, const int* __restrict__ dst,
    const int* __restrict__ rank, const int2* __restrict__ cinfo,
    const float* __restrict__ dinv, int2* __restrict__ csr2, int E, int n) {
  int e = blockIdx.x * 256 + threadIdx.x;
  if (e < E) {
    int d = dst[e];
    int s = src[e];
    int r = rank[e];
    int copy = (e >> 8) & (NCOPY - 1);
    int2 ni = cinfo[(size_t)copy * n + d];
    float norm = dinv[s] * __int_as_float(ni.y);
    csr2[ni.x + r] = make_int2(s, __float_as_int(norm));
  }
}

// ---- MFMA GEMM (128 cols) + int8 quant epilogue ---------------------------

template <bool A_IS_F32>
__global__ __launch_bounds__(256) void gemm_mfma_f128(
    const float* __restrict__ Af, const unsigned short* __restrict__ Ab,
    const unsigned short* __restrict__ Wt,
    signed char* __restrict__ xw8, float* __restrict__ xscale, int n) {
  __shared__ unsigned short shWt[HD * 136];   // [n][k], pad 8 bf16/row
  {
#pragma unroll
    for (int i = 0; i < 8; ++i) {
      int g = i * 256 + threadIdx.x;          // 16B chunk 0..2047
      int nrow = g >> 4, k16 = g & 15;
      uint4 v = *(const uint4*)(Wt + (size_t)g * 8);
      *(uint4*)(&shWt[nrow * 136 + k16 * 8]) = v;
    }
  }

  const int lane = threadIdx.x & 63;
  const int w = threadIdx.x >> 6;             // wave 0..3
  const int m = blockIdx.x * 64 + w * 16 + (lane & 15);
  const int mc = min(m, n - 1);
  const int kbase = (lane >> 4) * 8;          // 0,8,16,24

  bfrag af[4];
  if constexpr (A_IS_F32) {
    const float* ap = Af + (size_t)mc * HD + kbase;
#pragma unroll
    for (int kk = 0; kk < 4; ++kk) {
      float4 lo = *(const float4*)(ap + kk * 32);
      float4 hi = *(const float4*)(ap + kk * 32 + 4);
      bfrag a;
      a[0] = (short)f2bf(lo.x); a[1] = (short)f2bf(lo.y);
      a[2] = (short)f2bf(lo.z); a[3] = (short)f2bf(lo.w);
      a[4] = (short)f2bf(hi.x); a[5] = (short)f2bf(hi.y);
      a[6] = (short)f2bf(hi.z); a[7] = (short)f2bf(hi.w);
      af[kk] = a;
    }
  } else {
    const unsigned short* ap = Ab + (size_t)mc * HD + kbase;
#pragma unroll
    for (int kk = 0; kk < 4; ++kk) af[kk] = *(const bfrag*)(ap + kk * 32);
  }

  __syncthreads();

  facc acc[8];
#pragma unroll
  for (int c = 0; c < 8; ++c) {
    acc[c][0] = 0.f; acc[c][1] = 0.f; acc[c][2] = 0.f; acc[c][3] = 0.f;
  }

#pragma unroll
  for (int kk = 0; kk < 4; ++kk) {
#pragma unroll
    for (int c = 0; c < 8; ++c) {
      bfrag bf = *(const bfrag*)(&shWt[(c * 16 + (lane & 15)) * 136 + kk * 32 + kbase]);
      acc[c] = __builtin_amdgcn_mfma_f32_16x16x32_bf16(af[kk], bf, acc[c], 0, 0, 0);
    }
  }

  // C layout: col = lane&15, row = (lane>>4)*4 + q (within each 16-row tile).
  // Row absmax: reduce over 16 lanes (xor 1,2,4,8).
  float rmax[4];
#pragma unroll
  for (int q = 0; q < 4; ++q) {
    float mx = 0.f;
#pragma unroll
    for (int c = 0; c < 8; ++c) mx = fmaxf(mx, fabsf(acc[c][q]));
    rmax[q] = mx;
  }
#pragma unroll
  for (int off = 1; off < 16; off <<= 1) {
#pragma unroll
    for (int q = 0; q < 4; ++q) rmax[q] = fmaxf(rmax[q], __shfl_xor(rmax[q], off, 64));
  }

  const int rbase = blockIdx.x * 64 + w * 16 + (lane >> 4) * 4;
  const int col = lane & 15;
#pragma unroll
  for (int q = 0; q < 4; ++q) {
    int r = rbase + q;
    if (r < n) {
      float inv = (rmax[q] > 0.f) ? (127.f / rmax[q]) : 0.f;
      if (col == q) xscale[r] = rmax[q] * (1.f / 127.f);
#pragma unroll
      for (int c = 0; c < 8; ++c) {
        int v = __float2int_rn(acc[c][q] * inv);
        xw8[(size_t)r * HD + c * 16 + col] = (signed char)v;
      }
    }
  }
}

// ---- MFMA GEMM (40 cols, padded 48): xw40(bf16) = hb2 @ W3t^T --------------

__global__ __launch_bounds__(256) void gemm_mfma_f40(
    const unsigned short* __restrict__ Ab,   // bf16 h2 [n][128]
    const unsigned short* __restrict__ Wt,   // bf16 [48][128]
    unsigned short* __restrict__ out, int n) {
  __shared__ unsigned short shWt[48 * 136];
  {
#pragma unroll
    for (int i = 0; i < 3; ++i) {
      int g = i * 256 + threadIdx.x;          // 16B chunk 0..767
      int nrow = g >> 4, k16 = g & 15;
      uint4 v = *(const uint4*)(Wt + (size_t)g * 8);
      *(uint4*)(&shWt[nrow * 136 + k16 * 8]) = v;
    }
  }

  const int lane = threadIdx.x & 63;
  const int w = threadIdx.x >> 6;
  const int m = blockIdx.x * 64 + w * 16 + (lane & 15);
  const int mc = min(m, n - 1);
  const int kbase = (lane >> 4) * 8;

  bfrag af[4];
  const unsigned short* ap = Ab + (size_t)mc * HD + kbase;
#pragma unroll
  for (int kk = 0; kk < 4; ++kk) af[kk] = *(const bfrag*)(ap + kk * 32);

  __syncthreads();

  facc acc[3];
#pragma unroll
  for (int c = 0; c < 3; ++c) {
    acc[c][0] = 0.f; acc[c][1] = 0.f; acc[c][2] = 0.f; acc[c][3] = 0.f;
  }
#pragma unroll
  for (int kk = 0; kk < 4; ++kk) {
#pragma unroll
    for (int c = 0; c < 3; ++c) {
      bfrag bf = *(const bfrag*)(&shWt[(c * 16 + (lane & 15)) * 136 + kk * 32 + kbase]);
      acc[c] = __builtin_amdgcn_mfma_f32_16x16x32_bf16(af[kk], bf, acc[c], 0, 0, 0);
    }
  }

  const int rbase = blockIdx.x * 64 + w * 16 + (lane >> 4) * 4;
  const int col = lane & 15;
#pragma unroll
  for (int c = 0; c < 3; ++c) {
    int j = c * 16 + col;
    if (j < NC) {
#pragma unroll
      for (int q = 0; q < 4; ++q) {
        int r = rbase + q;
        if (r < n) out[(size_t)r * NC + j] = f2bf(acc[c][q]);
      }
    }
  }
}

// ---- aggregation, F=128 (int8): 4 nodes/wave, 16 lanes/node, uint2/lane ----
// RESID_F32: layer 1 (resid = x, f32); else resid = bf16 hb row. Output bf16.

template <bool RESID_F32>
__global__ __launch_bounds__(256) void agg_f128(
    const signed char* __restrict__ xw8, const float* __restrict__ xscale,
    const float* __restrict__ residf, const unsigned short* __restrict__ residb,
    const float* __restrict__ bias, const float* __restrict__ dinv,
    const int* __restrict__ row_start, const int* __restrict__ row_end,
    const int2* __restrict__ csr2, unsigned short* __restrict__ hbO, int n) {
  const int node = (blockIdx.x * 256 + threadIdx.x) >> 4;  // 16 threads/node
  if (node >= n) return;
  const int li = threadIdx.x & 15;
  const int f0 = li * 8;

  float di = dinv[node];
  float4 b01 = *(const float4*)(bias + f0);
  float4 b23 = *(const float4*)(bias + f0 + 4);
  // self term
  uint2 su = *(const uint2*)(xw8 + (size_t)node * HD + f0);
  float ssc = xscale[node] * di * di;
  float a0 = fmaf(db(su.x, 0), ssc, b01.x);
  float a1 = fmaf(db(su.x, 1), ssc, b01.y);
  float a2 = fmaf(db(su.x, 2), ssc, b01.z);
  float a3 = fmaf(db(su.x, 3), ssc, b01.w);
  float a4 = fmaf(db(su.y, 0), ssc, b23.x);
  float a5 = fmaf(db(su.y, 1), ssc, b23.y);
  float a6 = fmaf(db(su.y, 2), ssc, b23.z);
  float a7 = fmaf(db(su.y, 3), ssc, b23.w);

  int k = row_start[node];
  const int end = row_end[node];
  for (; k + 4 <= end; k += 4) {
    int4 p01 = *(const int4*)(csr2 + k);       // entries k, k+1
    int4 p23 = *(const int4*)(csr2 + k + 2);   // entries k+2, k+3
    uint2 u0 = *(const uint2*)(xw8 + (size_t)p01.x * HD + f0);
    uint2 u1 = *(const uint2*)(xw8 + (size_t)p01.z * HD + f0);
    uint2 u2 = *(const uint2*)(xw8 + (size_t)p23.x * HD + f0);
    uint2 u3 = *(const uint2*)(xw8 + (size_t)p23.z * HD + f0);
    float w0 = __int_as_float(p01.y) * xscale[p01.x];
    float w1 = __int_as_float(p01.w) * xscale[p01.z];
    float w2 = __int_as_float(p23.y) * xscale[p23.x];
    float w3 = __int_as_float(p23.w) * xscale[p23.z];
    a0 = fmaf(db(u0.x, 0), w0, a0); a1 = fmaf(db(u0.x, 1), w0, a1);
    a2 = fmaf(db(u0.x, 2), w0, a2); a3 = fmaf(db(u0.x, 3), w0, a3);
    a4 = fmaf(db(u0.y, 0), w0, a4); a5 = fmaf(db(u0.y, 1), w0, a5);
    a6 = fmaf(db(u0.y, 2), w0, a6); a7 = fmaf(db(u0.y, 3), w0, a7);
    a0 = fmaf(db(u1.x, 0), w1, a0); a1 = fmaf(db(u1.x, 1), w1, a1);
    a2 = fmaf(db(u1.x, 2), w1, a2); a3 = fmaf(db(u1.x, 3), w1, a3);
    a4 = fmaf(db(u1.y, 0), w1, a4); a5 = fmaf(db(u1.y, 1), w1, a5);
    a6 = fmaf(db(u1.y, 2), w1, a6); a7 = fmaf(db(u1.y, 3), w1, a7);
    a0 = fmaf(db(u2.x, 0), w2, a0); a1 = fmaf(db(u2.x, 1), w2, a1);
    a2 = fmaf(db(u2.x, 2), w2, a2); a3 = fmaf(db(u2.x, 3), w2, a3);
    a4 = fmaf(db(u2.y, 0), w2, a4); a5 = fmaf(db(u2.y, 1), w2, a5);
    a6 = fmaf(db(u2.y, 2), w2, a6); a7 = fmaf(db(u2.y, 3), w2, a7);
    a0 = fmaf(db(u3.x, 0), w3, a0); a1 = fmaf(db(u3.x, 1), w3, a1);
    a2 = fmaf(db(u3.x, 2), w3, a2); a3 = fmaf(db(u3.x, 3), w3, a3);
    a4 = fmaf(db(u3.y, 0), w3, a4); a5 = fmaf(db(u3.y, 1), w3, a5);
    a6 = fmaf(db(u3.y, 2), w3, a6); a7 = fmaf(db(u3.y, 3), w3, a7);
  }
  for (; k < end; ++k) {
    int2 c = csr2[k];
    uint2 u = *(const uint2*)(xw8 + (size_t)c.x * HD + f0);
    float w = __int_as_float(c.y) * xscale[c.x];
    a0 = fmaf(db(u.x, 0), w, a0); a1 = fmaf(db(u.x, 1), w, a1);
    a2 = fmaf(db(u.x, 2), w, a2); a3 = fmaf(db(u.x, 3), w, a3);
    a4 = fmaf(db(u.y, 0), w, a4); a5 = fmaf(db(u.y, 1), w, a5);
    a6 = fmaf(db(u.y, 2), w, a6); a7 = fmaf(db(u.y, 3), w, a7);
  }

  float r0, r1, r2, r3, r4, r5, r6, r7;
  if constexpr (RESID_F32) {
    float4 q0 = *(const float4*)(residf + (size_t)node * HD + f0);
    float4 q1 = *(const float4*)(residf + (size_t)node * HD + f0 + 4);
    r0 = q0.x; r1 = q0.y; r2 = q0.z; r3 = q0.w;
    r4 = q1.x; r5 = q1.y; r6 = q1.z; r7 = q1.w;
  } else {
    uint4 q = *(const uint4*)(residb + (size_t)node * HD + f0);
    float2 p0 = bf2f2(q.x), p1 = bf2f2(q.y), p2 = bf2f2(q.z), p3 = bf2f2(q.w);
    r0 = p0.x; r1 = p0.y; r2 = p1.x; r3 = p1.y;
    r4 = p2.x; r5 = p2.y; r6 = p3.x; r7 = p3.y;
  }
  uint4 hv;
  hv.x = packbf2(fmaxf(a0, 0.f) + r0, fmaxf(a1, 0.f) + r1);
  hv.y = packbf2(fmaxf(a2, 0.f) + r2, fmaxf(a3, 0.f) + r3);
  hv.z = packbf2(fmaxf(a4, 0.f) + r4, fmaxf(a5, 0.f) + r5);
  hv.w = packbf2(fmaxf(a6, 0.f) + r6, fmaxf(a7, 0.f) + r7);
  *(uint4*)(hbO + (size_t)node * HD + f0) = hv;
}

// ---- aggregation, F=40 + log_softmax: 4 nodes/wave, 16 lanes/node ---------

__global__ __launch_bounds__(256) void agg_f40_lsm(
    const unsigned short* __restrict__ xw, const float* __restrict__ dinv,
    const int* __restrict__ row_start, const int* __restrict__ row_end,
    const int2* __restrict__ csr2, const float* __restrict__ bias,
    float* __restrict__ out, int n) {
  const int node = (blockIdx.x * 256 + threadIdx.x) >> 4;
  if (node >= n) return;
  const int li = threadIdx.x & 15;
  const bool act = li < 10;
  const int f0 = li * 4;                 // 0..36 for active lanes

  float a0 = 0.f, a1 = 0.f, a2 = 0.f, a3 = 0.f;
  float di = dinv[node];
  if (act) {
    float4 bv = *(const float4*)(bias + f0);
    uint2 su = *(const uint2*)(xw + (size_t)node * NC + f0);
    float2 s0 = bf2f2(su.x), s1 = bf2f2(su.y);
    float ssc = di * di;
    a0 = fmaf(s0.x, ssc, bv.x);
    a1 = fmaf(s0.y, ssc, bv.y);
    a2 = fmaf(s1.x, ssc, bv.z);
    a3 = fmaf(s1.y, ssc, bv.w);
  }

  int k = row_start[node];
  const int end = row_end[node];
  for (; k + 4 <= end; k += 4) {
    int4 p01 = *(const int4*)(csr2 + k);
    int4 p23 = *(const int4*)(csr2 + k + 2);
    if (act) {
      uint2 u0 = *(const uint2*)(xw + (size_t)p01.x * NC + f0);
      uint2 u1 = *(const uint2*)(xw + (size_t)p01.z * NC + f0);
      uint2 u2 = *(const uint2*)(xw + (size_t)p23.x * NC + f0);
      uint2 u3 = *(const uint2*)(xw + (size_t)p23.z * NC + f0);
      float w0 = __int_as_float(p01.y), w1 = __int_as_float(p01.w);
      float w2 = __int_as_float(p23.y), w3 = __int_as_float(p23.w);
      float2 p, q;
      p = bf2f2(u0.x); q = bf2f2(u0.y);
      a0 = fmaf(p.x, w0, a0); a1 = fmaf(p.y, w0, a1);
      a2 = fmaf(q.x, w0, a2); a3 = fmaf(q.y, w0, a3);
      p = bf2f2(u1.x); q = bf2f2(u1.y);
      a0 = fmaf(p.x, w1, a0); a1 = fmaf(p.y, w1, a1);
      a2 = fmaf(q.x, w1, a2); a3 = fmaf(q.y, w1, a3);
      p = bf2f2(u2.x); q = bf2f2(u2.y);
      a0 = fmaf(p.x, w2, a0); a1 = fmaf(p.y, w2, a1);
      a2 = fmaf(q.x, w2, a2); a3 = fmaf(q.y, w2, a3);
      p = bf2f2(u3.x); q = bf2f2(u3.y);
      a0 = fmaf(p.x, w3, a0); a1 = fmaf(p.y, w3, a1);
      a2 = fmaf(q.x, w3, a2); a3 = fmaf(q.y, w3, a3);
    }
  }
  for (; k < end; ++k) {
    int2 c = csr2[k];
    if (act) {
      uint2 u = *(const uint2*)(xw + (size_t)c.x * NC + f0);
      float w = __int_as_float(c.y);
      float2 p = bf2f2(u.x), q = bf2f2(u.y);
      a0 = fmaf(p.x, w, a0); a1 = fmaf(p.y, w, a1);
      a2 = fmaf(q.x, w, a2); a3 = fmaf(q.y, w, a3);
    }
  }

  // log_softmax over the node's 40 values (10 lanes x 4), 16-lane xor reduce
  float m = act ? fmaxf(fmaxf(a0, a1), fmaxf(a2, a3)) : -3.0e38f;
  m = fmaxf(m, __shfl_xor(m, 1, 64));
  m = fmaxf(m, __shfl_xor(m, 2, 64));
  m = fmaxf(m, __shfl_xor(m, 4, 64));
  m = fmaxf(m, __shfl_xor(m, 8, 64));
  float s = act ? (expf(a0 - m) + expf(a1 - m) + expf(a2 - m) + expf(a3 - m)) : 0.f;
  s += __shfl_xor(s, 1, 64);
  s += __shfl_xor(s, 2, 64);
  s += __shfl_xor(s, 4, 64);
  s += __shfl_xor(s, 8, 64);
  if (act) {
    float lse = m + logf(s);
    float4 o;
    o.x = a0 - lse; o.y = a1 - lse; o.z = a2 - lse; o.w = a3 - lse;
    *(float4*)(out + (size_t)node * NC + f0) = o;
  }
}

// ---------------------------------------------------------------------------

extern "C" void kernel_launch(void* const* d_in, const int* in_sizes, int n_in,
                              void* d_out, int out_size, void* d_ws, size_t ws_size,
                              hipStream_t stream) {
  const float* x  = (const float*)d_in[0];
  const int*   ei = (const int*)d_in[1];
  const float* W1 = (const float*)d_in[2];
  const float* b1 = (const float*)d_in[3];
  const float* W2 = (const float*)d_in[4];
  const float* b2 = (const float*)d_in[5];
  const float* W3 = (const float*)d_in[6];
  const float* b3 = (const float*)d_in[7];
  float* out = (float*)d_out;

  const int n = in_sizes[0] / HD;  // 50000
  const int E = in_sizes[1] / 2;   // 800000
  const int* src = ei;
  const int* dst = ei + E;

  // workspace carve (all 256B-aligned)
  char* ws = (char*)d_ws;
  size_t off = 0;
  auto carve = [&](size_t bytes) -> void* {
    void* p = ws + off;
    off += (bytes + 255) & ~(size_t)255;
    return p;
  };
  int*   cnt8      = (int*)carve((size_t)n * NCOPY * 4);
  int*   row_start = (int*)carve((size_t)n * 4);
  int*   row_end   = (int*)carve((size_t)n * 4);
  float* dinv      = (float*)carve((size_t)n * 4);
  int2*  cinfo     = (int2*)carve((size_t)n * NCOPY * 8);
  int*   gtotal    = (int*)carve(256);
  unsigned short* w1t = (unsigned short*)carve((size_t)HD * HD * 2);
  unsigned short* w2t = (unsigned short*)carve((size_t)HD * HD * 2);
  unsigned short* w3t = (unsigned short*)carve((size_t)48 * HD * 2);
  int2*  csr2      = (int2*)carve((size_t)E * 8);
  signed char* xw8 = (signed char*)carve((size_t)n * HD);            // int8 xw
  float* xscale    = (float*)carve((size_t)n * 4);                   // row scales
  unsigned short* hb1  = (unsigned short*)carve((size_t)n * HD * 2); // bf16 h1
  unsigned short* hb2  = (unsigned short*)carve((size_t)n * HD * 2); // bf16 h2
  unsigned short* xw40 = (unsigned short*)carve((size_t)n * NC * 2); // bf16 xw3
  // rank[] dies after k_fill; xw8 is born at gemm1 -> alias (3.2MB <= 6.4MB).
  int*   rank      = (int*)xw8;

  const int gn8  = (n * NCOPY + 255) / 256;
  const int gE1  = (E + 255) / 256;       // 1 edge per thread
  const int gA   = (n + 15) / 16;         // 16 nodes per agg block
  const int gM   = (n + 63) / 64;         // 64 rows per mfma gemm block

  // fused prep (W preps + counter init), then CSR build
  k_prep<<<gn8 + 3, 256, 0, stream>>>(W1, W2, W3, w1t, w2t, w3t, cnt8, gtotal,
                                      n * NCOPY);
  k_count_rank<<<gE1, 256, 0, stream>>>(dst, cnt8, rank, E, n);
  k_alloc<<<(n + 255) / 256, 256, 0, stream>>>(cnt8, row_start, row_end, cinfo, dinv, gtotal, n);
  k_fill<<<gE1, 256, 0, stream>>>(src, dst, rank, cinfo, dinv, csr2, E, n);

  // layer 1: xw = x@W1 -> xw8+xscale ; h1 = relu(agg)+x -> hb1 (bf16)
  gemm_mfma_f128<true><<<gM, 256, 0, stream>>>(x, (const unsigned short*)nullptr, w1t, xw8, xscale, n);
  agg_f128<true><<<gA, 256, 0, stream>>>(xw8, xscale, x, (const unsigned short*)nullptr,
                                         b1, dinv, row_start, row_end, csr2, hb1, n);

  // layer 2: xw = h1@W2 -> xw8+xscale ; h2 = relu(agg)+h1 -> hb2 (bf16)
  gemm_mfma_f128<false><<<gM, 256, 0, stream>>>((const float*)nullptr, hb1, w2t, xw8, xscale, n);
  agg_f128<false><<<gA, 256, 0, stream>>>(xw8, xscale, (const float*)nullptr, hb1,
                                          b2, dinv, row_start, row_end, csr2, hb2, n);

  // layer 3: xw = h2@W3 -> xw40(bf16, MFMA) ; out = log_softmax(agg + b3)
  gemm_mfma_f40<<<gM, 256, 0, stream>>>(hb2, w3t, xw40, n);
  agg_f40_lsm<<<gA, 256, 0, stream>>>(xw40, dinv, row_start, row_end, csr2, b3, out, n);
}